// Round 4
// baseline (555.054 us; speedup 1.0000x reference)
//
#include <hip/hip_runtime.h>
#include <hip/hip_bf16.h>

#define N_NODES 100000
#define N_EDGES 1600000
#define D 64
#define BN_EPS 1e-5f
#define NB_SCAN 391  // ceil(N_NODES/256)
#define ROWSTR 68    // LDS row stride (floats): 68 mod 32 = 4 -> same even bank spread as 132

// ---------------- CSR build ----------------

__global__ __launch_bounds__(256) void k_hist4(const int* __restrict__ ei,
                                               int* __restrict__ deg) {
  int e = (blockIdx.x * 256 + threadIdx.x) * 4;
  if (e >= N_EDGES) return;
  int4 d = *(const int4*)(ei + N_EDGES + e);
  atomicAdd(&deg[d.x], 1);
  atomicAdd(&deg[d.y], 1);
  atomicAdd(&deg[d.z], 1);
  atomicAdd(&deg[d.w], 1);
}

// Per block: inclusive scan of deg, grab global base with one atomicAdd,
// write exclusive segment start into cursor. Segment placement order across
// blocks is arbitrary -- irrelevant to the final output.
__global__ __launch_bounds__(256) void k_offsets(const int* __restrict__ deg,
                                                 int* __restrict__ cursor,
                                                 int* __restrict__ gcount) {
  __shared__ int sd[256];
  __shared__ int sbase;
  int tid = threadIdx.x;
  int i = blockIdx.x * 256 + tid;
  int v = (i < N_NODES) ? deg[i] : 0;
  sd[tid] = v;
  __syncthreads();
  for (int ofs = 1; ofs < 256; ofs <<= 1) {
    int t = (tid >= ofs) ? sd[tid - ofs] : 0;
    __syncthreads();
    sd[tid] += t;
    __syncthreads();
  }
  if (tid == 255) sbase = atomicAdd(gcount, sd[255]);
  __syncthreads();
  if (i < N_NODES) cursor[i] = sbase + sd[tid] - v;  // exclusive start
}

// Advances cursor[dst] to segment end; gather recovers start = cursor - deg.
__global__ __launch_bounds__(256) void k_scatter4(const int* __restrict__ ei,
                                                  int* __restrict__ cursor,
                                                  int* __restrict__ ssrc) {
  int e = (blockIdx.x * 256 + threadIdx.x) * 4;
  if (e >= N_EDGES) return;
  int4 s = *(const int4*)(ei + e);
  int4 d = *(const int4*)(ei + N_EDGES + e);
  int p;
  p = atomicAdd(&cursor[d.x], 1); ssrc[p] = s.x;
  p = atomicAdd(&cursor[d.y], 1); ssrc[p] = s.y;
  p = atomicAdd(&cursor[d.z], 1); ssrc[p] = s.z;
  p = atomicAdd(&cursor[d.w], 1); ssrc[p] = s.w;
}

// ---------------- fused SAGE layer ----------------

template <bool BF>
__device__ inline float4 ld_quad(const void* p, long row, int q) {
  if constexpr (BF) {
    ushort4 u = *(const ushort4*)((const unsigned short*)p + row * D + q * 4);
    float4 f;
    unsigned int b;
    b = (unsigned int)u.x << 16; f.x = *(float*)&b;
    b = (unsigned int)u.y << 16; f.y = *(float*)&b;
    b = (unsigned int)u.z << 16; f.z = *(float*)&b;
    b = (unsigned int)u.w << 16; f.w = *(float*)&b;
    return f;
  } else {
    return *(const float4*)((const float*)p + row * D + q * 4);
  }
}

static __device__ inline unsigned short f2bf_bits(float v) {
  __hip_bfloat16 h = __float2bfloat16(v);
  return *reinterpret_cast<unsigned short*>(&h);
}

template <bool IN_BF16, bool OUT_BF16>
__global__ __launch_bounds__(256, 4) void sage_fused(
    const int* __restrict__ cursor, const int* __restrict__ deg_a,
    const int* __restrict__ ssrc, const void* __restrict__ xin,
    const float* __restrict__ wl, const float* __restrict__ bl,
    const float* __restrict__ wr,
    const float* __restrict__ gamma, const float* __restrict__ beta,
    const float* __restrict__ mean, const float* __restrict__ var,
    void* __restrict__ out) {
  __shared__ float in_t[64 * ROWSTR];  // agg only: 17.4 KB
  const int tid = threadIdx.x;
  const int base = blockIdx.x * 64;
  const int grp = tid >> 4;  // 16-lane group = node
  const int q = tid & 15;    // feature quad

  // phase 1: gather-aggregate. 8 independent row loads in flight per group.
  for (int p = 0; p < 4; ++p) {
    int r = p * 16 + grp;
    int n = base + r;
    float4 acc = make_float4(0.f, 0.f, 0.f, 0.f);
    if (n < N_NODES) {
      int end = cursor[n];
      int dg = deg_a[n];
      int st = end - dg;
      int u = 0;
      for (; u + 8 <= dg; u += 8) {
        int s0 = ssrc[st + u + 0], s1 = ssrc[st + u + 1];
        int s2 = ssrc[st + u + 2], s3 = ssrc[st + u + 3];
        int s4 = ssrc[st + u + 4], s5 = ssrc[st + u + 5];
        int s6 = ssrc[st + u + 6], s7 = ssrc[st + u + 7];
        float4 v0 = ld_quad<IN_BF16>(xin, s0, q);
        float4 v1 = ld_quad<IN_BF16>(xin, s1, q);
        float4 v2 = ld_quad<IN_BF16>(xin, s2, q);
        float4 v3 = ld_quad<IN_BF16>(xin, s3, q);
        float4 v4 = ld_quad<IN_BF16>(xin, s4, q);
        float4 v5 = ld_quad<IN_BF16>(xin, s5, q);
        float4 v6 = ld_quad<IN_BF16>(xin, s6, q);
        float4 v7 = ld_quad<IN_BF16>(xin, s7, q);
        acc.x += ((v0.x + v1.x) + (v2.x + v3.x)) + ((v4.x + v5.x) + (v6.x + v7.x));
        acc.y += ((v0.y + v1.y) + (v2.y + v3.y)) + ((v4.y + v5.y) + (v6.y + v7.y));
        acc.z += ((v0.z + v1.z) + (v2.z + v3.z)) + ((v4.z + v5.z) + (v6.z + v7.z));
        acc.w += ((v0.w + v1.w) + (v2.w + v3.w)) + ((v4.w + v5.w) + (v6.w + v7.w));
      }
      if (u + 4 <= dg) {
        int s0 = ssrc[st + u + 0], s1 = ssrc[st + u + 1];
        int s2 = ssrc[st + u + 2], s3 = ssrc[st + u + 3];
        float4 v0 = ld_quad<IN_BF16>(xin, s0, q);
        float4 v1 = ld_quad<IN_BF16>(xin, s1, q);
        float4 v2 = ld_quad<IN_BF16>(xin, s2, q);
        float4 v3 = ld_quad<IN_BF16>(xin, s3, q);
        acc.x += (v0.x + v1.x) + (v2.x + v3.x);
        acc.y += (v0.y + v1.y) + (v2.y + v3.y);
        acc.z += (v0.z + v1.z) + (v2.z + v3.z);
        acc.w += (v0.w + v1.w) + (v2.w + v3.w);
        u += 4;
      }
      for (; u < dg; ++u) {
        float4 v = ld_quad<IN_BF16>(xin, ssrc[st + u], q);
        acc.x += v.x; acc.y += v.y; acc.z += v.z; acc.w += v.w;
      }
      float invd = 1.0f / fmaxf((float)dg, 1.0f);
      acc.x *= invd; acc.y *= invd; acc.z *= invd; acc.w *= invd;
    }
    *(float4*)&in_t[r * ROWSTR + q * 4] = acc;
  }
  __syncthreads();

  // phase 2: thread = node (tid&63), wave = 16-dim block. Weights wave-uniform
  // -> SGPR loads. agg from LDS, x/h1 row straight from global (L1-hot).
  const int n = tid & 63;
  const int g = __builtin_amdgcn_readfirstlane(tid >> 6);  // 0..3
  const long gn = base + n;
  if (gn < N_NODES) {
    const float* inrow = &in_t[n * ROWSTR];
    for (int dt = 0; dt < 4; ++dt) {
      const int d0 = g * 16 + dt * 4;
      float a0 = bl[d0 + 0], a1 = bl[d0 + 1], a2 = bl[d0 + 2], a3 = bl[d0 + 3];
      const float* w0l = wl + (long)(d0 + 0) * 64;
      const float* w1l = wl + (long)(d0 + 1) * 64;
      const float* w2l = wl + (long)(d0 + 2) * 64;
      const float* w3l = wl + (long)(d0 + 3) * 64;
      const float* w0r = wr + (long)(d0 + 0) * 64;
      const float* w1r = wr + (long)(d0 + 1) * 64;
      const float* w2r = wr + (long)(d0 + 2) * 64;
      const float* w3r = wr + (long)(d0 + 3) * 64;
#pragma unroll
      for (int k = 0; k < 64; k += 4) {
        float4 iv = *(const float4*)(inrow + k);           // agg (LDS)
        float4 jv = ld_quad<IN_BF16>(xin, gn, k >> 2);     // x/h1 (global)
        a0 += iv.x * w0l[k] + iv.y * w0l[k + 1] + iv.z * w0l[k + 2] + iv.w * w0l[k + 3]
            + jv.x * w0r[k] + jv.y * w0r[k + 1] + jv.z * w0r[k + 2] + jv.w * w0r[k + 3];
        a1 += iv.x * w1l[k] + iv.y * w1l[k + 1] + iv.z * w1l[k + 2] + iv.w * w1l[k + 3]
            + jv.x * w1r[k] + jv.y * w1r[k + 1] + jv.z * w1r[k + 2] + jv.w * w1r[k + 3];
        a2 += iv.x * w2l[k] + iv.y * w2l[k + 1] + iv.z * w2l[k + 2] + iv.w * w2l[k + 3]
            + jv.x * w2r[k] + jv.y * w2r[k + 1] + jv.z * w2r[k + 2] + jv.w * w2r[k + 3];
        a3 += iv.x * w3l[k] + iv.y * w3l[k + 1] + iv.z * w3l[k + 2] + iv.w * w3l[k + 3]
            + jv.x * w3r[k] + jv.y * w3r[k + 1] + jv.z * w3r[k + 2] + jv.w * w3r[k + 3];
      }
      float sc0 = gamma[d0 + 0] * rsqrtf(var[d0 + 0] + BN_EPS);
      float sc1 = gamma[d0 + 1] * rsqrtf(var[d0 + 1] + BN_EPS);
      float sc2 = gamma[d0 + 2] * rsqrtf(var[d0 + 2] + BN_EPS);
      float sc3 = gamma[d0 + 3] * rsqrtf(var[d0 + 3] + BN_EPS);
      float sh0 = beta[d0 + 0] - mean[d0 + 0] * sc0;
      float sh1 = beta[d0 + 1] - mean[d0 + 1] * sc1;
      float sh2 = beta[d0 + 2] - mean[d0 + 2] * sc2;
      float sh3 = beta[d0 + 3] - mean[d0 + 3] * sc3;
      float o0 = a0 > 0.f ? a0 : expm1f(a0);
      float o1 = a1 > 0.f ? a1 : expm1f(a1);
      float o2 = a2 > 0.f ? a2 : expm1f(a2);
      float o3 = a3 > 0.f ? a3 : expm1f(a3);
      o0 = o0 * sc0 + sh0; o1 = o1 * sc1 + sh1;
      o2 = o2 * sc2 + sh2; o3 = o3 * sc3 + sh3;
      if constexpr (OUT_BF16) {
        ushort4 pk;
        pk.x = f2bf_bits(o0); pk.y = f2bf_bits(o1);
        pk.z = f2bf_bits(o2); pk.w = f2bf_bits(o3);
        *(ushort4*)((unsigned short*)out + gn * D + d0) = pk;
      } else {
        float4 f;
        f.x = o0; f.y = o1; f.z = o2; f.w = o3;
        *(float4*)((float*)out + gn * D + d0) = f;
      }
    }
  }
}

// ---------------- launch ----------------

extern "C" void kernel_launch(void* const* d_in, const int* in_sizes, int n_in,
                              void* d_out, int out_size, void* d_ws, size_t ws_size,
                              hipStream_t stream) {
  const float* x     = (const float*)d_in[0];
  const int*   ei    = (const int*)d_in[1];
  const float* w1_l  = (const float*)d_in[2];
  const float* b1_l  = (const float*)d_in[3];
  const float* w1_r  = (const float*)d_in[4];
  const float* w2_l  = (const float*)d_in[5];
  const float* b2_l  = (const float*)d_in[6];
  const float* w2_r  = (const float*)d_in[7];
  const float* bn1_g = (const float*)d_in[8];
  const float* bn1_b = (const float*)d_in[9];
  const float* bn1_m = (const float*)d_in[10];
  const float* bn1_v = (const float*)d_in[11];
  const float* bn2_g = (const float*)d_in[12];
  const float* bn2_b = (const float*)d_in[13];
  const float* bn2_m = (const float*)d_in[14];
  const float* bn2_v = (const float*)d_in[15];

  // ws layout (~20.0 MB)
  int* deg    = (int*)d_ws;          // [N]
  int* gcount = deg + N_NODES;       // [1] (+pad to 100008)
  int* cursor = deg + 100008;        // [N]
  int* ssrc   = cursor + 100008;     // [E]
  unsigned short* h1 = (unsigned short*)(ssrc + N_EDGES);  // bf16 [N*D]

  const int eb4 = (N_EDGES / 4 + 255) / 256;
  const int tiles = (N_NODES + 63) / 64;

  hipMemsetAsync(deg, 0, 100008 * sizeof(int), stream);  // deg + gcount
  k_hist4<<<eb4, 256, 0, stream>>>(ei, deg);
  k_offsets<<<NB_SCAN, 256, 0, stream>>>(deg, cursor, gcount);
  k_scatter4<<<eb4, 256, 0, stream>>>(ei, cursor, ssrc);

  sage_fused<false, true><<<tiles, 256, 0, stream>>>(
      cursor, deg, ssrc, x, w1_l, b1_l, w1_r, bn1_g, bn1_b, bn1_m, bn1_v, h1);
  sage_fused<true, false><<<tiles, 256, 0, stream>>>(
      cursor, deg, ssrc, h1, w2_l, b2_l, w2_r, bn2_g, bn2_b, bn2_m, bn2_v, d_out);
}

// Round 5
// 543.688 us; speedup vs baseline: 1.0209x; 1.0209x over previous
//
#include <hip/hip_runtime.h>
#include <hip/hip_bf16.h>

#define N_NODES 100000
#define N_EDGES 1600000
#define D 64
#define BN_EPS 1e-5f
#define NB_SCAN 391   // ceil(N_NODES/256)
#define AGS 68        // agg LDS row stride (floats)
#define XRS 68        // x-row LDS stride (shorts); 8B-aligned quads, 4 lanes/bank = min aliasing

// ---------------- CSR build ----------------

__global__ __launch_bounds__(256) void k_hist4(const int* __restrict__ ei,
                                               int* __restrict__ deg) {
  int e = (blockIdx.x * 256 + threadIdx.x) * 4;
  if (e >= N_EDGES) return;
  int4 d = *(const int4*)(ei + N_EDGES + e);
  atomicAdd(&deg[d.x], 1);
  atomicAdd(&deg[d.y], 1);
  atomicAdd(&deg[d.z], 1);
  atomicAdd(&deg[d.w], 1);
}

// Per-block scan + one atomicAdd for segment base; placement order arbitrary.
__global__ __launch_bounds__(256) void k_offsets(const int* __restrict__ deg,
                                                 int* __restrict__ cursor,
                                                 int* __restrict__ gcount) {
  __shared__ int sd[256];
  __shared__ int sbase;
  int tid = threadIdx.x;
  int i = blockIdx.x * 256 + tid;
  int v = (i < N_NODES) ? deg[i] : 0;
  sd[tid] = v;
  __syncthreads();
  for (int ofs = 1; ofs < 256; ofs <<= 1) {
    int t = (tid >= ofs) ? sd[tid - ofs] : 0;
    __syncthreads();
    sd[tid] += t;
    __syncthreads();
  }
  if (tid == 255) sbase = atomicAdd(gcount, sd[255]);
  __syncthreads();
  if (i < N_NODES) cursor[i] = sbase + sd[tid] - v;  // exclusive start
}

__global__ __launch_bounds__(256) void k_scatter4(const int* __restrict__ ei,
                                                  int* __restrict__ cursor,
                                                  int* __restrict__ ssrc) {
  int e = (blockIdx.x * 256 + threadIdx.x) * 4;
  if (e >= N_EDGES) return;
  int4 s = *(const int4*)(ei + e);
  int4 d = *(const int4*)(ei + N_EDGES + e);
  int p;
  p = atomicAdd(&cursor[d.x], 1); ssrc[p] = s.x;
  p = atomicAdd(&cursor[d.y], 1); ssrc[p] = s.y;
  p = atomicAdd(&cursor[d.z], 1); ssrc[p] = s.z;
  p = atomicAdd(&cursor[d.w], 1); ssrc[p] = s.w;
}

// ---------------- helpers ----------------

static __device__ inline unsigned short f2bf_bits(float v) {
  __hip_bfloat16 h = __float2bfloat16(v);
  return *reinterpret_cast<unsigned short*>(&h);
}

static __device__ inline float4 bf4_to_f4(ushort4 u) {
  float4 f;
  unsigned int b;
  b = (unsigned int)u.x << 16; f.x = *(float*)&b;
  b = (unsigned int)u.y << 16; f.y = *(float*)&b;
  b = (unsigned int)u.z << 16; f.z = *(float*)&b;
  b = (unsigned int)u.w << 16; f.w = *(float*)&b;
  return f;
}

template <bool BF>
__device__ inline float4 ld_quad(const void* p, long row, int q) {
  if constexpr (BF) {
    return bf4_to_f4(*(const ushort4*)((const unsigned short*)p + row * D + q * 4));
  } else {
    return *(const float4*)((const float*)p + row * D + q * 4);
  }
}

// x f32 -> bf16 copy (layer-1 gather source)
__global__ __launch_bounds__(256) void k_cvt(const float* __restrict__ x,
                                             unsigned short* __restrict__ xb) {
  long i = (long)(blockIdx.x * 256 + threadIdx.x) * 4;
  if (i >= (long)N_NODES * D) return;
  float4 v = *(const float4*)(x + i);
  ushort4 u;
  u.x = f2bf_bits(v.x); u.y = f2bf_bits(v.y);
  u.z = f2bf_bits(v.z); u.w = f2bf_bits(v.w);
  *(ushort4*)(xb + i) = u;
}

// ---------------- fused SAGE layer ----------------
// Phase 1: gather-aggregate neighbor rows; stage agg (f32) + root row (bf16)
// in LDS. Phase 2: wave-uniform SGPR weights, all row data from LDS (keeps
// output lines write-combining in L2 -- round-4 regression lesson).

template <bool IN_BF16, bool OUT_BF16>
__global__ __launch_bounds__(256, 4) void sage_fused(
    const int* __restrict__ cursor, const int* __restrict__ deg_a,
    const int* __restrict__ ssrc, const void* __restrict__ xin,
    const float* __restrict__ wl, const float* __restrict__ bl,
    const float* __restrict__ wr,
    const float* __restrict__ gamma, const float* __restrict__ beta,
    const float* __restrict__ mean, const float* __restrict__ var,
    void* __restrict__ out) {
  __shared__ float in_t[64 * AGS];            // agg, f32: 17408 B
  __shared__ unsigned short xr_t[64 * XRS];   // root row, bf16: 8704 B
  const int tid = threadIdx.x;
  const int base = blockIdx.x * 64;
  const int grp = tid >> 4;  // 16-lane group = node
  const int q = tid & 15;    // feature quad

  // phase 1
  for (int p = 0; p < 4; ++p) {
    int r = p * 16 + grp;
    int n = base + r;
    float4 acc = make_float4(0.f, 0.f, 0.f, 0.f);
    ushort4 xu = make_ushort4(0, 0, 0, 0);
    if (n < N_NODES) {
      int end = cursor[n];
      int dg = deg_a[n];
      int st = end - dg;
      int u = 0;
      for (; u + 8 <= dg; u += 8) {
        int s0 = ssrc[st + u + 0], s1 = ssrc[st + u + 1];
        int s2 = ssrc[st + u + 2], s3 = ssrc[st + u + 3];
        int s4 = ssrc[st + u + 4], s5 = ssrc[st + u + 5];
        int s6 = ssrc[st + u + 6], s7 = ssrc[st + u + 7];
        float4 v0 = ld_quad<IN_BF16>(xin, s0, q);
        float4 v1 = ld_quad<IN_BF16>(xin, s1, q);
        float4 v2 = ld_quad<IN_BF16>(xin, s2, q);
        float4 v3 = ld_quad<IN_BF16>(xin, s3, q);
        float4 v4 = ld_quad<IN_BF16>(xin, s4, q);
        float4 v5 = ld_quad<IN_BF16>(xin, s5, q);
        float4 v6 = ld_quad<IN_BF16>(xin, s6, q);
        float4 v7 = ld_quad<IN_BF16>(xin, s7, q);
        acc.x += ((v0.x + v1.x) + (v2.x + v3.x)) + ((v4.x + v5.x) + (v6.x + v7.x));
        acc.y += ((v0.y + v1.y) + (v2.y + v3.y)) + ((v4.y + v5.y) + (v6.y + v7.y));
        acc.z += ((v0.z + v1.z) + (v2.z + v3.z)) + ((v4.z + v5.z) + (v6.z + v7.z));
        acc.w += ((v0.w + v1.w) + (v2.w + v3.w)) + ((v4.w + v5.w) + (v6.w + v7.w));
      }
      if (u + 4 <= dg) {
        int s0 = ssrc[st + u + 0], s1 = ssrc[st + u + 1];
        int s2 = ssrc[st + u + 2], s3 = ssrc[st + u + 3];
        float4 v0 = ld_quad<IN_BF16>(xin, s0, q);
        float4 v1 = ld_quad<IN_BF16>(xin, s1, q);
        float4 v2 = ld_quad<IN_BF16>(xin, s2, q);
        float4 v3 = ld_quad<IN_BF16>(xin, s3, q);
        acc.x += (v0.x + v1.x) + (v2.x + v3.x);
        acc.y += (v0.y + v1.y) + (v2.y + v3.y);
        acc.z += (v0.z + v1.z) + (v2.z + v3.z);
        acc.w += (v0.w + v1.w) + (v2.w + v3.w);
        u += 4;
      }
      for (; u < dg; ++u) {
        float4 v = ld_quad<IN_BF16>(xin, ssrc[st + u], q);
        acc.x += v.x; acc.y += v.y; acc.z += v.z; acc.w += v.w;
      }
      float invd = 1.0f / fmaxf((float)dg, 1.0f);
      acc.x *= invd; acc.y *= invd; acc.z *= invd; acc.w *= invd;
      if constexpr (IN_BF16) {
        xu = *(const ushort4*)((const unsigned short*)xin + (long)n * D + q * 4);
      } else {
        float4 xv = *(const float4*)((const float*)xin + (long)n * D + q * 4);
        xu.x = f2bf_bits(xv.x); xu.y = f2bf_bits(xv.y);
        xu.z = f2bf_bits(xv.z); xu.w = f2bf_bits(xv.w);
      }
    }
    *(float4*)&in_t[r * AGS + q * 4] = acc;
    *(ushort4*)&xr_t[r * XRS + q * 4] = xu;
  }
  __syncthreads();

  // phase 2: thread = node (tid&63), wave = 16-dim block; SGPR weights.
  const int n = tid & 63;
  const int g = __builtin_amdgcn_readfirstlane(tid >> 6);  // 0..3
  const long gn = base + n;
  if (gn < N_NODES) {
    const float* arow = &in_t[n * AGS];
    const unsigned short* xrow = &xr_t[n * XRS];
    for (int dt = 0; dt < 4; ++dt) {
      const int d0 = g * 16 + dt * 4;
      float a0 = bl[d0 + 0], a1 = bl[d0 + 1], a2 = bl[d0 + 2], a3 = bl[d0 + 3];
      const float* w0l = wl + (long)(d0 + 0) * 64;
      const float* w1l = wl + (long)(d0 + 1) * 64;
      const float* w2l = wl + (long)(d0 + 2) * 64;
      const float* w3l = wl + (long)(d0 + 3) * 64;
      const float* w0r = wr + (long)(d0 + 0) * 64;
      const float* w1r = wr + (long)(d0 + 1) * 64;
      const float* w2r = wr + (long)(d0 + 2) * 64;
      const float* w3r = wr + (long)(d0 + 3) * 64;
#pragma unroll
      for (int k = 0; k < 64; k += 4) {
        float4 iv = *(const float4*)(arow + k);              // agg (LDS f32)
        float4 jv = bf4_to_f4(*(const ushort4*)(xrow + k));  // root (LDS bf16)
        a0 += iv.x * w0l[k] + iv.y * w0l[k + 1] + iv.z * w0l[k + 2] + iv.w * w0l[k + 3]
            + jv.x * w0r[k] + jv.y * w0r[k + 1] + jv.z * w0r[k + 2] + jv.w * w0r[k + 3];
        a1 += iv.x * w1l[k] + iv.y * w1l[k + 1] + iv.z * w1l[k + 2] + iv.w * w1l[k + 3]
            + jv.x * w1r[k] + jv.y * w1r[k + 1] + jv.z * w1r[k + 2] + jv.w * w1r[k + 3];
        a2 += iv.x * w2l[k] + iv.y * w2l[k + 1] + iv.z * w2l[k + 2] + iv.w * w2l[k + 3]
            + jv.x * w2r[k] + jv.y * w2r[k + 1] + jv.z * w2r[k + 2] + jv.w * w2r[k + 3];
        a3 += iv.x * w3l[k] + iv.y * w3l[k + 1] + iv.z * w3l[k + 2] + iv.w * w3l[k + 3]
            + jv.x * w3r[k] + jv.y * w3r[k + 1] + jv.z * w3r[k + 2] + jv.w * w3r[k + 3];
      }
      float sc0 = gamma[d0 + 0] * rsqrtf(var[d0 + 0] + BN_EPS);
      float sc1 = gamma[d0 + 1] * rsqrtf(var[d0 + 1] + BN_EPS);
      float sc2 = gamma[d0 + 2] * rsqrtf(var[d0 + 2] + BN_EPS);
      float sc3 = gamma[d0 + 3] * rsqrtf(var[d0 + 3] + BN_EPS);
      float sh0 = beta[d0 + 0] - mean[d0 + 0] * sc0;
      float sh1 = beta[d0 + 1] - mean[d0 + 1] * sc1;
      float sh2 = beta[d0 + 2] - mean[d0 + 2] * sc2;
      float sh3 = beta[d0 + 3] - mean[d0 + 3] * sc3;
      float o0 = a0 > 0.f ? a0 : expm1f(a0);
      float o1 = a1 > 0.f ? a1 : expm1f(a1);
      float o2 = a2 > 0.f ? a2 : expm1f(a2);
      float o3 = a3 > 0.f ? a3 : expm1f(a3);
      o0 = o0 * sc0 + sh0; o1 = o1 * sc1 + sh1;
      o2 = o2 * sc2 + sh2; o3 = o3 * sc3 + sh3;
      if constexpr (OUT_BF16) {
        ushort4 pk;
        pk.x = f2bf_bits(o0); pk.y = f2bf_bits(o1);
        pk.z = f2bf_bits(o2); pk.w = f2bf_bits(o3);
        *(ushort4*)((unsigned short*)out + gn * D + d0) = pk;
      } else {
        float4 f;
        f.x = o0; f.y = o1; f.z = o2; f.w = o3;
        *(float4*)((float*)out + gn * D + d0) = f;
      }
    }
  }
}

// ---------------- launch ----------------

extern "C" void kernel_launch(void* const* d_in, const int* in_sizes, int n_in,
                              void* d_out, int out_size, void* d_ws, size_t ws_size,
                              hipStream_t stream) {
  const float* x     = (const float*)d_in[0];
  const int*   ei    = (const int*)d_in[1];
  const float* w1_l  = (const float*)d_in[2];
  const float* b1_l  = (const float*)d_in[3];
  const float* w1_r  = (const float*)d_in[4];
  const float* w2_l  = (const float*)d_in[5];
  const float* b2_l  = (const float*)d_in[6];
  const float* w2_r  = (const float*)d_in[7];
  const float* bn1_g = (const float*)d_in[8];
  const float* bn1_b = (const float*)d_in[9];
  const float* bn1_m = (const float*)d_in[10];
  const float* bn1_v = (const float*)d_in[11];
  const float* bn2_g = (const float*)d_in[12];
  const float* bn2_b = (const float*)d_in[13];
  const float* bn2_m = (const float*)d_in[14];
  const float* bn2_v = (const float*)d_in[15];

  // ws layout
  int* deg    = (int*)d_ws;          // [N] (+pad, gcount at N)
  int* gcount = deg + N_NODES;       // [1]
  int* cursor = deg + 100008;        // [N] (+pad)
  int* ssrc   = cursor + 100008;     // [E]
  unsigned short* h1 = (unsigned short*)(ssrc + N_EDGES);   // bf16 [N*D] (12.8 MB)
  unsigned short* xb = h1 + (size_t)N_NODES * D;            // bf16 [N*D] (12.8 MB)
  const size_t need_xb = (size_t)(100008 + 100008 + N_EDGES) * 4
                       + (size_t)N_NODES * D * 2 * 2;
  const bool use_xb = ws_size >= need_xb;

  const int eb4 = (N_EDGES / 4 + 255) / 256;
  const int tiles = (N_NODES + 63) / 64;

  hipMemsetAsync(deg, 0, 100008 * sizeof(int), stream);  // deg + gcount
  k_hist4<<<eb4, 256, 0, stream>>>(ei, deg);
  k_offsets<<<NB_SCAN, 256, 0, stream>>>(deg, cursor, gcount);
  k_scatter4<<<eb4, 256, 0, stream>>>(ei, cursor, ssrc);

  if (use_xb) {
    k_cvt<<<(N_NODES * D / 4 + 255) / 256, 256, 0, stream>>>(x, xb);
    sage_fused<true, true><<<tiles, 256, 0, stream>>>(
        cursor, deg, ssrc, xb, w1_l, b1_l, w1_r, bn1_g, bn1_b, bn1_m, bn1_v, h1);
  } else {
    sage_fused<false, true><<<tiles, 256, 0, stream>>>(
        cursor, deg, ssrc, x, w1_l, b1_l, w1_r, bn1_g, bn1_b, bn1_m, bn1_v, h1);
  }
  sage_fused<true, false><<<tiles, 256, 0, stream>>>(
      cursor, deg, ssrc, h1, w2_l, b2_l, w2_r, bn2_g, bn2_b, bn2_m, bn2_v, d_out);
}

// Round 6
// 405.701 us; speedup vs baseline: 1.3681x; 1.3401x over previous
//
#include <hip/hip_runtime.h>
#include <hip/hip_bf16.h>

#define N_NODES 100000
#define N_EDGES 1600000
#define D 64
#define BN_EPS 1e-5f
#define NB_SCAN 391  // ceil(N_NODES/256)
#define ROWSTR 132   // in_t row stride (floats): 16B-aligned quads, even bank spread

// ---------------- CSR build ----------------
// k_hist_rank: histogram in-degree AND capture each edge's rank within its
// dst segment (the atomicAdd return value). rank < 2^15 (in-degree is
// ~Poisson(16), max ~60 for this graph). tmp[e] = src | rank<<17 (src<2^17).

__global__ __launch_bounds__(256) void k_hist_rank(const int* __restrict__ ei,
                                                   int* __restrict__ deg,
                                                   int* __restrict__ tmp) {
  int e = (blockIdx.x * 256 + threadIdx.x) * 4;
  if (e >= N_EDGES) return;
  int4 s = *(const int4*)(ei + e);
  int4 d = *(const int4*)(ei + N_EDGES + e);
  int4 t;
  t.x = s.x | (atomicAdd(&deg[d.x], 1) << 17);
  t.y = s.y | (atomicAdd(&deg[d.y], 1) << 17);
  t.z = s.z | (atomicAdd(&deg[d.z], 1) << 17);
  t.w = s.w | (atomicAdd(&deg[d.w], 1) << 17);
  *(int4*)(tmp + e) = t;
}

// Per-block scan + one atomicAdd for segment base; placement order arbitrary.
__global__ __launch_bounds__(256) void k_offsets(const int* __restrict__ deg,
                                                 int* __restrict__ cursor,
                                                 int* __restrict__ gcount) {
  __shared__ int sd[256];
  __shared__ int sbase;
  int tid = threadIdx.x;
  int i = blockIdx.x * 256 + tid;
  int v = (i < N_NODES) ? deg[i] : 0;
  sd[tid] = v;
  __syncthreads();
  for (int ofs = 1; ofs < 256; ofs <<= 1) {
    int t = (tid >= ofs) ? sd[tid - ofs] : 0;
    __syncthreads();
    sd[tid] += t;
    __syncthreads();
  }
  if (tid == 255) sbase = atomicAdd(gcount, sd[255]);
  __syncthreads();
  if (i < N_NODES) cursor[i] = sbase + sd[tid] - v;  // exclusive segment start
}

// Atomic-free scatter: pos = start[dst] + rank.
__global__ __launch_bounds__(256) void k_scatter_rank(const int* __restrict__ ei,
                                                      const int* __restrict__ tmp,
                                                      const int* __restrict__ cursor,
                                                      int* __restrict__ ssrc) {
  int e = (blockIdx.x * 256 + threadIdx.x) * 4;
  if (e >= N_EDGES) return;
  int4 d = *(const int4*)(ei + N_EDGES + e);
  int4 t = *(const int4*)(tmp + e);
  ssrc[cursor[d.x] + ((unsigned)t.x >> 17)] = t.x & 0x1ffff;
  ssrc[cursor[d.y] + ((unsigned)t.y >> 17)] = t.y & 0x1ffff;
  ssrc[cursor[d.z] + ((unsigned)t.z >> 17)] = t.z & 0x1ffff;
  ssrc[cursor[d.w] + ((unsigned)t.w >> 17)] = t.w & 0x1ffff;
}

// ---------------- fused SAGE layer (round-3 proven structure) ----------------

template <bool BF>
__device__ inline float4 ld_quad(const void* p, long row, int q) {
  if constexpr (BF) {
    ushort4 u = *(const ushort4*)((const unsigned short*)p + row * D + q * 4);
    float4 f;
    unsigned int b;
    b = (unsigned int)u.x << 16; f.x = *(float*)&b;
    b = (unsigned int)u.y << 16; f.y = *(float*)&b;
    b = (unsigned int)u.z << 16; f.z = *(float*)&b;
    b = (unsigned int)u.w << 16; f.w = *(float*)&b;
    return f;
  } else {
    return *(const float4*)((const float*)p + row * D + q * 4);
  }
}

static __device__ inline unsigned short f2bf_bits(float v) {
  __hip_bfloat16 h = __float2bfloat16(v);
  return *reinterpret_cast<unsigned short*>(&h);
}

template <bool IN_BF16, bool OUT_BF16>
__global__ __launch_bounds__(256) void sage_fused(
    const int* __restrict__ cursor, const int* __restrict__ deg_a,
    const int* __restrict__ ssrc, const void* __restrict__ xin,
    const float* __restrict__ wl, const float* __restrict__ bl,
    const float* __restrict__ wr,
    const float* __restrict__ gamma, const float* __restrict__ beta,
    const float* __restrict__ mean, const float* __restrict__ var,
    void* __restrict__ out) {
  __shared__ float in_t[64 * ROWSTR];
  const int tid = threadIdx.x;
  const int base = blockIdx.x * 64;
  const int grp = tid >> 4;  // 16-lane group = node
  const int q = tid & 15;    // feature quad

  // phase 1: gather-aggregate. group = node; lane = 4 features. 4 passes.
  for (int p = 0; p < 4; ++p) {
    int r = p * 16 + grp;
    int n = base + r;
    float4 acc = make_float4(0.f, 0.f, 0.f, 0.f);
    float4 xv = make_float4(0.f, 0.f, 0.f, 0.f);
    if (n < N_NODES) {
      int st = cursor[n];
      int dg = deg_a[n];
      int u = 0;
      for (; u + 4 <= dg; u += 4) {
        int s0 = ssrc[st + u + 0];
        int s1 = ssrc[st + u + 1];
        int s2 = ssrc[st + u + 2];
        int s3 = ssrc[st + u + 3];
        float4 v0 = ld_quad<IN_BF16>(xin, s0, q);
        float4 v1 = ld_quad<IN_BF16>(xin, s1, q);
        float4 v2 = ld_quad<IN_BF16>(xin, s2, q);
        float4 v3 = ld_quad<IN_BF16>(xin, s3, q);
        acc.x += (v0.x + v1.x) + (v2.x + v3.x);
        acc.y += (v0.y + v1.y) + (v2.y + v3.y);
        acc.z += (v0.z + v1.z) + (v2.z + v3.z);
        acc.w += (v0.w + v1.w) + (v2.w + v3.w);
      }
      for (; u < dg; ++u) {
        float4 v = ld_quad<IN_BF16>(xin, ssrc[st + u], q);
        acc.x += v.x; acc.y += v.y; acc.z += v.z; acc.w += v.w;
      }
      float invd = 1.0f / fmaxf((float)dg, 1.0f);
      acc.x *= invd; acc.y *= invd; acc.z *= invd; acc.w *= invd;
      xv = ld_quad<IN_BF16>(xin, n, q);
    }
    *(float4*)&in_t[r * ROWSTR + q * 4] = acc;
    *(float4*)&in_t[r * ROWSTR + 64 + q * 4] = xv;
  }
  __syncthreads();

  // phase 2: thread = (node = tid&63, dim-block g = wave). Weights wave-uniform
  // -> SGPR loads. All row data from LDS (round-4 lesson: keep phase 2 off
  // global reads so output lines write-combine).
  const int n = tid & 63;
  const int g = __builtin_amdgcn_readfirstlane(tid >> 6);  // 0..3
  const long gn = base + n;
  const float* inrow = &in_t[n * ROWSTR];

  for (int dt = 0; dt < 4; ++dt) {
    const int d0 = g * 16 + dt * 4;
    float a0 = bl[d0 + 0], a1 = bl[d0 + 1], a2 = bl[d0 + 2], a3 = bl[d0 + 3];
    const float* w0l = wl + (long)(d0 + 0) * 64;
    const float* w1l = wl + (long)(d0 + 1) * 64;
    const float* w2l = wl + (long)(d0 + 2) * 64;
    const float* w3l = wl + (long)(d0 + 3) * 64;
    const float* w0r = wr + (long)(d0 + 0) * 64;
    const float* w1r = wr + (long)(d0 + 1) * 64;
    const float* w2r = wr + (long)(d0 + 2) * 64;
    const float* w3r = wr + (long)(d0 + 3) * 64;
#pragma unroll
    for (int k = 0; k < 64; k += 4) {
      float4 iv = *(const float4*)(inrow + k);       // agg half
      float4 jv = *(const float4*)(inrow + 64 + k);  // x half
      a0 += iv.x * w0l[k] + iv.y * w0l[k + 1] + iv.z * w0l[k + 2] + iv.w * w0l[k + 3]
          + jv.x * w0r[k] + jv.y * w0r[k + 1] + jv.z * w0r[k + 2] + jv.w * w0r[k + 3];
      a1 += iv.x * w1l[k] + iv.y * w1l[k + 1] + iv.z * w1l[k + 2] + iv.w * w1l[k + 3]
          + jv.x * w1r[k] + jv.y * w1r[k + 1] + jv.z * w1r[k + 2] + jv.w * w1r[k + 3];
      a2 += iv.x * w2l[k] + iv.y * w2l[k + 1] + iv.z * w2l[k + 2] + iv.w * w2l[k + 3]
          + jv.x * w2r[k] + jv.y * w2r[k + 1] + jv.z * w2r[k + 2] + jv.w * w2r[k + 3];
      a3 += iv.x * w3l[k] + iv.y * w3l[k + 1] + iv.z * w3l[k + 2] + iv.w * w3l[k + 3]
          + jv.x * w3r[k] + jv.y * w3r[k + 1] + jv.z * w3r[k + 2] + jv.w * w3r[k + 3];
    }
    if (gn < N_NODES) {
      float sc0 = gamma[d0 + 0] * rsqrtf(var[d0 + 0] + BN_EPS);
      float sc1 = gamma[d0 + 1] * rsqrtf(var[d0 + 1] + BN_EPS);
      float sc2 = gamma[d0 + 2] * rsqrtf(var[d0 + 2] + BN_EPS);
      float sc3 = gamma[d0 + 3] * rsqrtf(var[d0 + 3] + BN_EPS);
      float sh0 = beta[d0 + 0] - mean[d0 + 0] * sc0;
      float sh1 = beta[d0 + 1] - mean[d0 + 1] * sc1;
      float sh2 = beta[d0 + 2] - mean[d0 + 2] * sc2;
      float sh3 = beta[d0 + 3] - mean[d0 + 3] * sc3;
      float o0 = a0 > 0.f ? a0 : expm1f(a0);
      float o1 = a1 > 0.f ? a1 : expm1f(a1);
      float o2 = a2 > 0.f ? a2 : expm1f(a2);
      float o3 = a3 > 0.f ? a3 : expm1f(a3);
      o0 = o0 * sc0 + sh0; o1 = o1 * sc1 + sh1;
      o2 = o2 * sc2 + sh2; o3 = o3 * sc3 + sh3;
      if constexpr (OUT_BF16) {
        ushort4 pk;
        pk.x = f2bf_bits(o0); pk.y = f2bf_bits(o1);
        pk.z = f2bf_bits(o2); pk.w = f2bf_bits(o3);
        *(ushort4*)((unsigned short*)out + gn * D + d0) = pk;
      } else {
        float4 f;
        f.x = o0; f.y = o1; f.z = o2; f.w = o3;
        *(float4*)((float*)out + gn * D + d0) = f;
      }
    }
  }
}

// ---------------- launch ----------------

extern "C" void kernel_launch(void* const* d_in, const int* in_sizes, int n_in,
                              void* d_out, int out_size, void* d_ws, size_t ws_size,
                              hipStream_t stream) {
  const float* x     = (const float*)d_in[0];
  const int*   ei    = (const int*)d_in[1];
  const float* w1_l  = (const float*)d_in[2];
  const float* b1_l  = (const float*)d_in[3];
  const float* w1_r  = (const float*)d_in[4];
  const float* w2_l  = (const float*)d_in[5];
  const float* b2_l  = (const float*)d_in[6];
  const float* w2_r  = (const float*)d_in[7];
  const float* bn1_g = (const float*)d_in[8];
  const float* bn1_b = (const float*)d_in[9];
  const float* bn1_m = (const float*)d_in[10];
  const float* bn1_v = (const float*)d_in[11];
  const float* bn2_g = (const float*)d_in[12];
  const float* bn2_b = (const float*)d_in[13];
  const float* bn2_m = (const float*)d_in[14];
  const float* bn2_v = (const float*)d_in[15];

  // ws layout (20.0 MB total):
  int* deg    = (int*)d_ws;          // [N] (+pad, gcount at N)
  int* gcount = deg + N_NODES;       // [1]
  int* cursor = deg + 100008;        // [N] segment starts
  int* ssrc   = cursor + 100008;     // [E]
  unsigned short* h1 = (unsigned short*)(ssrc + N_EDGES);  // bf16 [N*D], 12.8 MB
  int* tmp    = (int*)h1;            // [E] rank|src, aliases h1 (dead until layer 1)

  const int eb4 = (N_EDGES / 4 + 255) / 256;
  const int tiles = (N_NODES + 63) / 64;

  hipMemsetAsync(deg, 0, 100008 * sizeof(int), stream);  // deg + gcount
  k_hist_rank<<<eb4, 256, 0, stream>>>(ei, deg, tmp);
  k_offsets<<<NB_SCAN, 256, 0, stream>>>(deg, cursor, gcount);
  k_scatter_rank<<<eb4, 256, 0, stream>>>(ei, tmp, cursor, ssrc);

  sage_fused<false, true><<<tiles, 256, 0, stream>>>(
      cursor, deg, ssrc, x, w1_l, b1_l, w1_r, bn1_g, bn1_b, bn1_m, bn1_v, h1);
  sage_fused<true, false><<<tiles, 256, 0, stream>>>(
      cursor, deg, ssrc, h1, w2_l, b2_l, w2_r, bn2_g, bn2_b, bn2_m, bn2_v, d_out);
}

// Round 7
// 362.827 us; speedup vs baseline: 1.5298x; 1.1182x over previous
//
#include <hip/hip_runtime.h>
#include <hip/hip_bf16.h>

#define N_NODES 100000
#define N_EDGES 1600000
#define D 64
#define BN_EPS 1e-5f
#define NB_SCAN 391  // ceil(N_NODES/256)
#define ROWSTR 132   // in_t row stride (floats): 16B-aligned quads, even bank spread

// ---------------- CSR build (round-6 proven) ----------------

__global__ __launch_bounds__(256) void k_hist_rank(const int* __restrict__ ei,
                                                   int* __restrict__ deg,
                                                   int* __restrict__ tmp) {
  int e = (blockIdx.x * 256 + threadIdx.x) * 4;
  if (e >= N_EDGES) return;
  int4 s = *(const int4*)(ei + e);
  int4 d = *(const int4*)(ei + N_EDGES + e);
  int4 t;
  t.x = s.x | (atomicAdd(&deg[d.x], 1) << 17);
  t.y = s.y | (atomicAdd(&deg[d.y], 1) << 17);
  t.z = s.z | (atomicAdd(&deg[d.z], 1) << 17);
  t.w = s.w | (atomicAdd(&deg[d.w], 1) << 17);
  *(int4*)(tmp + e) = t;
}

__global__ __launch_bounds__(256) void k_offsets(const int* __restrict__ deg,
                                                 int* __restrict__ cursor,
                                                 int* __restrict__ gcount) {
  __shared__ int sd[256];
  __shared__ int sbase;
  int tid = threadIdx.x;
  int i = blockIdx.x * 256 + tid;
  int v = (i < N_NODES) ? deg[i] : 0;
  sd[tid] = v;
  __syncthreads();
  for (int ofs = 1; ofs < 256; ofs <<= 1) {
    int t = (tid >= ofs) ? sd[tid - ofs] : 0;
    __syncthreads();
    sd[tid] += t;
    __syncthreads();
  }
  if (tid == 255) sbase = atomicAdd(gcount, sd[255]);
  __syncthreads();
  if (i < N_NODES) cursor[i] = sbase + sd[tid] - v;  // exclusive segment start
}

__global__ __launch_bounds__(256) void k_scatter_rank(const int* __restrict__ ei,
                                                      const int* __restrict__ tmp,
                                                      const int* __restrict__ cursor,
                                                      int* __restrict__ ssrc) {
  int e = (blockIdx.x * 256 + threadIdx.x) * 4;
  if (e >= N_EDGES) return;
  int4 d = *(const int4*)(ei + N_EDGES + e);
  int4 t = *(const int4*)(tmp + e);
  ssrc[cursor[d.x] + ((unsigned)t.x >> 17)] = t.x & 0x1ffff;
  ssrc[cursor[d.y] + ((unsigned)t.y >> 17)] = t.y & 0x1ffff;
  ssrc[cursor[d.z] + ((unsigned)t.z >> 17)] = t.z & 0x1ffff;
  ssrc[cursor[d.w] + ((unsigned)t.w >> 17)] = t.w & 0x1ffff;
}

// ---------------- helpers ----------------

static __device__ inline unsigned short f2bf_bits(float v) {
  __hip_bfloat16 h = __float2bfloat16(v);
  return *reinterpret_cast<unsigned short*>(&h);
}

// add 8 bf16 (one uint4 = 16B) into f32 accumulators
static __device__ inline void add_bf8(float* a, uint4 v) {
  unsigned int b;
  b = v.x << 16;         a[0] += *(float*)&b;
  b = v.x & 0xffff0000u; a[1] += *(float*)&b;
  b = v.y << 16;         a[2] += *(float*)&b;
  b = v.y & 0xffff0000u; a[3] += *(float*)&b;
  b = v.z << 16;         a[4] += *(float*)&b;
  b = v.z & 0xffff0000u; a[5] += *(float*)&b;
  b = v.w << 16;         a[6] += *(float*)&b;
  b = v.w & 0xffff0000u; a[7] += *(float*)&b;
}

static __device__ inline void set_bf8(float* a, uint4 v) {
  unsigned int b;
  b = v.x << 16;         a[0] = *(float*)&b;
  b = v.x & 0xffff0000u; a[1] = *(float*)&b;
  b = v.y << 16;         a[2] = *(float*)&b;
  b = v.y & 0xffff0000u; a[3] = *(float*)&b;
  b = v.z << 16;         a[4] = *(float*)&b;
  b = v.z & 0xffff0000u; a[5] = *(float*)&b;
  b = v.w << 16;         a[6] = *(float*)&b;
  b = v.w & 0xffff0000u; a[7] = *(float*)&b;
}

// x f32 -> bf16 copy (into upper half of d_out; dead until layer 2 rewrites)
__global__ __launch_bounds__(256) void k_cvt(const float* __restrict__ x,
                                             unsigned short* __restrict__ xb) {
  long i = (long)(blockIdx.x * 256 + threadIdx.x) * 4;
  if (i >= (long)N_NODES * D) return;
  float4 v = *(const float4*)(x + i);
  ushort4 u;
  u.x = f2bf_bits(v.x); u.y = f2bf_bits(v.y);
  u.z = f2bf_bits(v.z); u.w = f2bf_bits(v.w);
  *(ushort4*)(xb + i) = u;
}

// ---------------- fused SAGE layer ----------------
// Gather source is ALWAYS bf16 (xb for layer 1, h1 for layer 2): 8 lanes/row,
// uint4 (16B) loads -> half the load count of the f32 gather. Root row source
// is f32 x (layer 1, keeps lin_r path exact) or bf16 h1 (layer 2).
// Phase 2: round-3/6 proven structure (all row data from LDS, SGPR weights).

template <bool ROOT_BF16, bool OUT_BF16>
__global__ __launch_bounds__(256) void sage_fused(
    const int* __restrict__ cursor, const int* __restrict__ deg_a,
    const int* __restrict__ ssrc,
    const unsigned short* __restrict__ gsrc,  // bf16 gather table [N][D]
    const void* __restrict__ rsrc,            // root rows: f32 or bf16 [N][D]
    const float* __restrict__ wl, const float* __restrict__ bl,
    const float* __restrict__ wr,
    const float* __restrict__ gamma, const float* __restrict__ beta,
    const float* __restrict__ mean, const float* __restrict__ var,
    void* __restrict__ out) {
  __shared__ float in_t[64 * ROWSTR];
  const int tid = threadIdx.x;
  const int base = blockIdx.x * 64;
  const int grp = tid >> 3;  // 8-lane group = node (32 groups)
  const int q8 = tid & 7;    // 16B chunk = 8 bf16 features

  // phase 1: gather-aggregate. 8 loads in flight per group (64/wave). 2 passes.
  for (int p = 0; p < 2; ++p) {
    int r = p * 32 + grp;
    int n = base + r;
    float a[8] = {0.f, 0.f, 0.f, 0.f, 0.f, 0.f, 0.f, 0.f};
    float xr[8] = {0.f, 0.f, 0.f, 0.f, 0.f, 0.f, 0.f, 0.f};
    if (n < N_NODES) {
      int st = cursor[n];
      int dg = deg_a[n];
      int u = 0;
      for (; u + 8 <= dg; u += 8) {
        int s0 = ssrc[st + u + 0], s1 = ssrc[st + u + 1];
        int s2 = ssrc[st + u + 2], s3 = ssrc[st + u + 3];
        int s4 = ssrc[st + u + 4], s5 = ssrc[st + u + 5];
        int s6 = ssrc[st + u + 6], s7 = ssrc[st + u + 7];
        uint4 v0 = *((const uint4*)(gsrc + (long)s0 * D) + q8);
        uint4 v1 = *((const uint4*)(gsrc + (long)s1 * D) + q8);
        uint4 v2 = *((const uint4*)(gsrc + (long)s2 * D) + q8);
        uint4 v3 = *((const uint4*)(gsrc + (long)s3 * D) + q8);
        uint4 v4 = *((const uint4*)(gsrc + (long)s4 * D) + q8);
        uint4 v5 = *((const uint4*)(gsrc + (long)s5 * D) + q8);
        uint4 v6 = *((const uint4*)(gsrc + (long)s6 * D) + q8);
        uint4 v7 = *((const uint4*)(gsrc + (long)s7 * D) + q8);
        add_bf8(a, v0); add_bf8(a, v1); add_bf8(a, v2); add_bf8(a, v3);
        add_bf8(a, v4); add_bf8(a, v5); add_bf8(a, v6); add_bf8(a, v7);
      }
      if (u + 4 <= dg) {
        int s0 = ssrc[st + u + 0], s1 = ssrc[st + u + 1];
        int s2 = ssrc[st + u + 2], s3 = ssrc[st + u + 3];
        uint4 v0 = *((const uint4*)(gsrc + (long)s0 * D) + q8);
        uint4 v1 = *((const uint4*)(gsrc + (long)s1 * D) + q8);
        uint4 v2 = *((const uint4*)(gsrc + (long)s2 * D) + q8);
        uint4 v3 = *((const uint4*)(gsrc + (long)s3 * D) + q8);
        add_bf8(a, v0); add_bf8(a, v1); add_bf8(a, v2); add_bf8(a, v3);
        u += 4;
      }
      for (; u < dg; ++u) {
        uint4 v = *((const uint4*)(gsrc + (long)ssrc[st + u] * D) + q8);
        add_bf8(a, v);
      }
      float invd = 1.0f / fmaxf((float)dg, 1.0f);
#pragma unroll
      for (int j = 0; j < 8; ++j) a[j] *= invd;
      if constexpr (ROOT_BF16) {
        uint4 v = *((const uint4*)((const unsigned short*)rsrc + (long)n * D) + q8);
        set_bf8(xr, v);
      } else {
        float4 f0 = *((const float4*)((const float*)rsrc + (long)n * D) + q8 * 2);
        float4 f1 = *((const float4*)((const float*)rsrc + (long)n * D) + q8 * 2 + 1);
        xr[0] = f0.x; xr[1] = f0.y; xr[2] = f0.z; xr[3] = f0.w;
        xr[4] = f1.x; xr[5] = f1.y; xr[6] = f1.z; xr[7] = f1.w;
      }
    }
    *(float4*)&in_t[r * ROWSTR + q8 * 8 + 0] = make_float4(a[0], a[1], a[2], a[3]);
    *(float4*)&in_t[r * ROWSTR + q8 * 8 + 4] = make_float4(a[4], a[5], a[6], a[7]);
    *(float4*)&in_t[r * ROWSTR + 64 + q8 * 8 + 0] = make_float4(xr[0], xr[1], xr[2], xr[3]);
    *(float4*)&in_t[r * ROWSTR + 64 + q8 * 8 + 4] = make_float4(xr[4], xr[5], xr[6], xr[7]);
  }
  __syncthreads();

  // phase 2: thread = (node = tid&63, dim-block g = wave). SGPR weights,
  // all row data from LDS (round-4 lesson).
  const int n = tid & 63;
  const int g = __builtin_amdgcn_readfirstlane(tid >> 6);  // 0..3
  const long gn = base + n;
  const float* inrow = &in_t[n * ROWSTR];

  for (int dt = 0; dt < 4; ++dt) {
    const int d0 = g * 16 + dt * 4;
    float a0 = bl[d0 + 0], a1 = bl[d0 + 1], a2 = bl[d0 + 2], a3 = bl[d0 + 3];
    const float* w0l = wl + (long)(d0 + 0) * 64;
    const float* w1l = wl + (long)(d0 + 1) * 64;
    const float* w2l = wl + (long)(d0 + 2) * 64;
    const float* w3l = wl + (long)(d0 + 3) * 64;
    const float* w0r = wr + (long)(d0 + 0) * 64;
    const float* w1r = wr + (long)(d0 + 1) * 64;
    const float* w2r = wr + (long)(d0 + 2) * 64;
    const float* w3r = wr + (long)(d0 + 3) * 64;
#pragma unroll
    for (int k = 0; k < 64; k += 4) {
      float4 iv = *(const float4*)(inrow + k);       // agg half
      float4 jv = *(const float4*)(inrow + 64 + k);  // root half
      a0 += iv.x * w0l[k] + iv.y * w0l[k + 1] + iv.z * w0l[k + 2] + iv.w * w0l[k + 3]
          + jv.x * w0r[k] + jv.y * w0r[k + 1] + jv.z * w0r[k + 2] + jv.w * w0r[k + 3];
      a1 += iv.x * w1l[k] + iv.y * w1l[k + 1] + iv.z * w1l[k + 2] + iv.w * w1l[k + 3]
          + jv.x * w1r[k] + jv.y * w1r[k + 1] + jv.z * w1r[k + 2] + jv.w * w1r[k + 3];
      a2 += iv.x * w2l[k] + iv.y * w2l[k + 1] + iv.z * w2l[k + 2] + iv.w * w2l[k + 3]
          + jv.x * w2r[k] + jv.y * w2r[k + 1] + jv.z * w2r[k + 2] + jv.w * w2r[k + 3];
      a3 += iv.x * w3l[k] + iv.y * w3l[k + 1] + iv.z * w3l[k + 2] + iv.w * w3l[k + 3]
          + jv.x * w3r[k] + jv.y * w3r[k + 1] + jv.z * w3r[k + 2] + jv.w * w3r[k + 3];
    }
    if (gn < N_NODES) {
      float sc0 = gamma[d0 + 0] * rsqrtf(var[d0 + 0] + BN_EPS);
      float sc1 = gamma[d0 + 1] * rsqrtf(var[d0 + 1] + BN_EPS);
      float sc2 = gamma[d0 + 2] * rsqrtf(var[d0 + 2] + BN_EPS);
      float sc3 = gamma[d0 + 3] * rsqrtf(var[d0 + 3] + BN_EPS);
      float sh0 = beta[d0 + 0] - mean[d0 + 0] * sc0;
      float sh1 = beta[d0 + 1] - mean[d0 + 1] * sc1;
      float sh2 = beta[d0 + 2] - mean[d0 + 2] * sc2;
      float sh3 = beta[d0 + 3] - mean[d0 + 3] * sc3;
      float o0 = a0 > 0.f ? a0 : expm1f(a0);
      float o1 = a1 > 0.f ? a1 : expm1f(a1);
      float o2 = a2 > 0.f ? a2 : expm1f(a2);
      float o3 = a3 > 0.f ? a3 : expm1f(a3);
      o0 = o0 * sc0 + sh0; o1 = o1 * sc1 + sh1;
      o2 = o2 * sc2 + sh2; o3 = o3 * sc3 + sh3;
      if constexpr (OUT_BF16) {
        ushort4 pk;
        pk.x = f2bf_bits(o0); pk.y = f2bf_bits(o1);
        pk.z = f2bf_bits(o2); pk.w = f2bf_bits(o3);
        *(ushort4*)((unsigned short*)out + gn * D + d0) = pk;
      } else {
        float4 f;
        f.x = o0; f.y = o1; f.z = o2; f.w = o3;
        *(float4*)((float*)out + gn * D + d0) = f;
      }
    }
  }
}

// ---------------- launch ----------------

extern "C" void kernel_launch(void* const* d_in, const int* in_sizes, int n_in,
                              void* d_out, int out_size, void* d_ws, size_t ws_size,
                              hipStream_t stream) {
  const float* x     = (const float*)d_in[0];
  const int*   ei    = (const int*)d_in[1];
  const float* w1_l  = (const float*)d_in[2];
  const float* b1_l  = (const float*)d_in[3];
  const float* w1_r  = (const float*)d_in[4];
  const float* w2_l  = (const float*)d_in[5];
  const float* b2_l  = (const float*)d_in[6];
  const float* w2_r  = (const float*)d_in[7];
  const float* bn1_g = (const float*)d_in[8];
  const float* bn1_b = (const float*)d_in[9];
  const float* bn1_m = (const float*)d_in[10];
  const float* bn1_v = (const float*)d_in[11];
  const float* bn2_g = (const float*)d_in[12];
  const float* bn2_b = (const float*)d_in[13];
  const float* bn2_m = (const float*)d_in[14];
  const float* bn2_v = (const float*)d_in[15];

  // ws layout (20.0 MB):
  int* deg    = (int*)d_ws;          // [N] (+pad, gcount at N)
  int* gcount = deg + N_NODES;       // [1]
  int* cursor = deg + 100008;        // [N] segment starts
  int* ssrc   = cursor + 100008;     // [E]
  unsigned short* h1 = (unsigned short*)(ssrc + N_EDGES);  // bf16 [N*D], 12.8 MB
  int* tmp    = (int*)h1;            // [E] rank|src, aliases h1 (dead until layer 1)

  // bf16 copy of x in the UPPER HALF of d_out (bytes [12.8MB, 25.6MB)).
  // Dead by the time layer 2 rewrites all of d_out; layer 1 only reads it.
  unsigned short* xb = (unsigned short*)d_out + (size_t)N_NODES * D;

  const int eb4 = (N_EDGES / 4 + 255) / 256;
  const int tiles = (N_NODES + 63) / 64;

  hipMemsetAsync(deg, 0, 100008 * sizeof(int), stream);  // deg + gcount
  k_hist_rank<<<eb4, 256, 0, stream>>>(ei, deg, tmp);
  k_offsets<<<NB_SCAN, 256, 0, stream>>>(deg, cursor, gcount);
  k_scatter_rank<<<eb4, 256, 0, stream>>>(ei, tmp, cursor, ssrc);
  k_cvt<<<(N_NODES * D / 4 + 255) / 256, 256, 0, stream>>>(x, xb);

  // layer 1: gather bf16 xb, root f32 x -> bf16 h1
  sage_fused<false, true><<<tiles, 256, 0, stream>>>(
      cursor, deg, ssrc, xb, x, w1_l, b1_l, w1_r,
      bn1_g, bn1_b, bn1_m, bn1_v, h1);
  // layer 2: gather bf16 h1, root bf16 h1 -> f32 d_out
  sage_fused<true, false><<<tiles, 256, 0, stream>>>(
      cursor, deg, ssrc, h1, h1, w2_l, b2_l, w2_r,
      bn2_g, bn2_b, bn2_m, bn2_v, d_out);
}